// Round 13
// baseline (37.410 us; speedup 1.0000x reference)
//
#include <hip/hip_runtime.h>

// BiorUpSampling: 2x zero-interleaved upsample + separable symmetric 9-tap
// filter, SAME zero padding. Polyphase, register-streaming 5-row ring,
// 2-deep prefetch, NT stores. R13: 4 input cols/thread, float4 center load:
// read-instruction density halved (3 loads/row for 4 cols vs 6), horizontal
// read redundancy 3x -> 1.75x, coarser read bursts into the write stream.
// Block = 256 thr = 2 row-halves x 128 col-threads; 512 blocks, 8 waves/CU.

constexpr int H = 512, W = 512;
constexpr int RP  = 8;    // rows per thread-group -> 16 output rows
constexpr int RPB = 16;   // rows per block (two half-groups)

typedef float f32x4 __attribute__((ext_vector_type(4)));
typedef float f32x2 __attribute__((ext_vector_type(2)));

__global__ __launch_bounds__(256, 4)
void bior_up_kernel(const float* __restrict__ in, float* __restrict__ out) {
  constexpr float E0 =  0.03782845550699535f;
  constexpr float E1 = -0.1106244044184226f;
  constexpr float E2 =  0.8526986790094022f;
  constexpr float E3 = -0.1106244044184226f;
  constexpr float E4 =  0.03782845550699535f;
  constexpr float O0 = -0.02384946501937986f;
  constexpr float O1 =  0.3774028556126536f;
  constexpr float O2 =  0.3774028556126537f;
  constexpr float O3 = -0.02384946501937986f;

  const int t  = threadIdx.x;
  const int rh = t >> 7;            // row-half 0/1
  const int ct = t & 127;           // col-thread 0..127
  const int cc = ct * 4;            // first input col (0..508), 16B aligned
  const int r0 = blockIdx.x * RPB + rh * RP;
  const int b  = blockIdx.y;
  const float* inb  = in  + (size_t)b * H * W;
  float*       outb = out + (size_t)b * (2 * H) * (2 * W);

  const bool lvv = (cc >= 2);       // left halo cols cc-2,cc-1 in bounds
  const bool rvv = (cc + 5 < W);    // right halo cols cc+4,cc+5 in bounds

  struct Raw { f32x4 M; f32x2 L, R; };   // v0..v7 = cols cc-2 .. cc+5
  auto loadrow = [&](int gr, Raw& w) {
    const bool rowv = ((unsigned)gr < (unsigned)H);
    const float* rowp = inb + (size_t)gr * W;
    w.M = rowv ? *reinterpret_cast<const f32x4*>(rowp + cc) : (f32x4)0.f;
    w.L = (rowv && lvv) ? *reinterpret_cast<const f32x2*>(rowp + cc - 2) : (f32x2)0.f;
    w.R = (rowv && rvv) ? *reinterpret_cast<const f32x2*>(rowp + cc + 4) : (f32x2)0.f;
  };
  // Horizontal polyphase: hE[j] -> out col 2(cc+j), hO[j] -> out col 2(cc+j)+1
  auto hfilt = [&](const Raw& w, f32x4& hE, f32x4& hO) {
    const float v0 = w.L.x, v1 = w.L.y, v2 = w.M.x, v3 = w.M.y,
                v4 = w.M.z, v5 = w.M.w, v6 = w.R.x, v7 = w.R.y;
    const f32x4 va = {v0, v1, v2, v3};
    const f32x4 vb = {v1, v2, v3, v4};
    const f32x4 vc = {v2, v3, v4, v5};
    const f32x4 vd = {v3, v4, v5, v6};
    const f32x4 ve = {v4, v5, v6, v7};
    hE = va*E0 + vb*E1 + vc*E2 + vd*E3 + ve*E4;
    hO = vb*O0 + vc*O1 + vd*O2 + ve*O3;
  };

  // Ring of h-filtered rows; slot k holds row (center-2+k).
  f32x4 rE[5], rO[5];

  // Prologue: 6 lead-in rows, loads issued back-to-back.
  Raw ra, rb, rc, rd, w0, w1, w2;
  loadrow(r0 - 2, ra);
  loadrow(r0 - 1, rb);
  loadrow(r0    , rc);
  loadrow(r0 + 1, rd);
  loadrow(r0 + 2, w0);   // consumed at p=0
  loadrow(r0 + 3, w1);   // consumed at p=1
  hfilt(ra, rE[0], rO[0]);
  hfilt(rb, rE[1], rO[1]);
  hfilt(rc, rE[2], rO[2]);
  hfilt(rd, rE[3], rO[3]);

#pragma unroll
  for (int p = 0; p < RP; ++p) {
    if (p + 2 < RP) loadrow(r0 + 4 + p, w2);   // 2-deep prefetch

    hfilt(w0, rE[4], rO[4]);                   // consume oldest preload

    // Vertical polyphase over the ring.
    const f32x4 EE = rE[0]*E0 + rE[1]*E1 + rE[2]*E2 + rE[3]*E3 + rE[4]*E4;
    const f32x4 EO = rO[0]*E0 + rO[1]*E1 + rO[2]*E2 + rO[3]*E3 + rO[4]*E4;
    const f32x4 OE = rE[1]*O0 + rE[2]*O1 + rE[3]*O2 + rE[4]*O3;
    const f32x4 OO = rO[1]*O0 + rO[2]*O1 + rO[3]*O2 + rO[4]*O3;

    // Interleave even/odd output columns: out cols 8*ct .. 8*ct+7.
    const f32x4 s0 = {EE.x, EO.x, EE.y, EO.y};
    const f32x4 s1 = {EE.z, EO.z, EE.w, EO.w};
    const f32x4 s2 = {OE.x, OO.x, OE.y, OO.y};
    const f32x4 s3 = {OE.z, OO.z, OE.w, OO.w};

    const int row_e = 2 * (r0 + p);
    float* pe = &outb[(size_t)row_e       * (2 * W) + 8 * ct];
    float* po = &outb[(size_t)(row_e + 1) * (2 * W) + 8 * ct];
    __builtin_nontemporal_store(s0, reinterpret_cast<f32x4*>(pe));
    __builtin_nontemporal_store(s1, reinterpret_cast<f32x4*>(pe + 4));
    __builtin_nontemporal_store(s2, reinterpret_cast<f32x4*>(po));
    __builtin_nontemporal_store(s3, reinterpret_cast<f32x4*>(po + 4));

#pragma unroll
    for (int k = 0; k < 4; ++k) { rE[k] = rE[k + 1]; rO[k] = rO[k + 1]; }
    w0 = w1; w1 = w2;
  }
}

extern "C" void kernel_launch(void* const* d_in, const int* in_sizes, int n_in,
                              void* d_out, int out_size, void* d_ws, size_t ws_size,
                              hipStream_t stream) {
  const float* in = (const float*)d_in[0];
  float* out = (float*)d_out;
  const int batch = in_sizes[0] / (H * W);
  dim3 grid(H / RPB, batch);   // 32 x 16 = 512 blocks
  bior_up_kernel<<<grid, 256, 0, stream>>>(in, out);
}

// Round 14
// 19.317 us; speedup vs baseline: 1.9366x; 1.9366x over previous
//
#include <hip/hip_runtime.h>

// BiorUpSampling: 2x zero-interleaved upsample + separable symmetric 9-tap
// filter, SAME zero padding. Polyphase, register-streaming 5-row ring,
// NT stores, interleaved loop (R10 structure) with a 4-DEEP load pipeline.
// R10's VGPR_Count=40 proved the compiler sank the source-level prefetch
// back to its uses (40 regs can't hold ring+2-row prefetch); launch_bounds
// (256,4) grants a 128-VGPR budget so the pipeline physically exists.

constexpr int H = 512, W = 512;
constexpr int RP = 8;   // input rows advanced per block -> 16 output rows
constexpr int PD = 4;   // prefetch depth (rows of loads in flight)

typedef float f32x4 __attribute__((ext_vector_type(4)));

__global__ __launch_bounds__(256, 4)
void bior_up_kernel(const float* __restrict__ in, float* __restrict__ out) {
  constexpr float E0 =  0.03782845550699535f;
  constexpr float E1 = -0.1106244044184226f;
  constexpr float E2 =  0.8526986790094022f;
  constexpr float E3 = -0.1106244044184226f;
  constexpr float E4 =  0.03782845550699535f;
  constexpr float O0 = -0.02384946501937986f;
  constexpr float O1 =  0.3774028556126536f;
  constexpr float O2 =  0.3774028556126537f;
  constexpr float O3 = -0.02384946501937986f;

  const int tid = threadIdx.x;
  const int r0  = blockIdx.x * RP;
  const int b   = blockIdx.y;
  const float* inb  = in  + (size_t)b * H * W;
  float*       outb = out + (size_t)b * (2 * H) * (2 * W);

  const int c = 2 * tid;              // this thread's input cols: c, c+1
  const bool lv = (c >= 2);
  const bool rv = (c <= W - 4);

  auto loadrow = [&](int gr, float2& L, float2& M, float2& R) {
    const bool rowv = ((unsigned)gr < (unsigned)H);
    const float* rowp = inb + (size_t)gr * W;
    const float2 z = make_float2(0.0f, 0.0f);
    L = (rowv && lv) ? *reinterpret_cast<const float2*>(rowp + c - 2) : z;
    M =  rowv        ? *reinterpret_cast<const float2*>(rowp + c)     : z;
    R = (rowv && rv) ? *reinterpret_cast<const float2*>(rowp + c + 2) : z;
  };
  auto hfilt = [&](float2 L, float2 M, float2 R,
                   float& a, float& bb, float& cc, float& dd) {
    const float v0 = L.x, v1 = L.y, v2 = M.x, v3 = M.y, v4 = R.x, v5 = R.y;
    a  = v0*E0 + v1*E1 + v2*E2 + v3*E3 + v4*E4;   // he(c)   -> out col 2c
    bb = v1*O0 + v2*O1 + v3*O2 + v4*O3;           // ho(c)   -> out col 2c+1
    cc = v1*E0 + v2*E1 + v3*E2 + v4*E3 + v5*E4;   // he(c+1) -> out col 2c+2
    dd = v2*O0 + v3*O1 + v4*O2 + v5*O3;           // ho(c+1) -> out col 2c+3
  };

  // Ring of horizontally-filtered rows; slot k holds row (center-2+k).
  float A[5], B[5], C[5], D[5];

  // Prefetch FIFO, PD rows deep (constant-indexed after full unroll).
  float2 Lf[PD], Mf[PD], Rf[PD];

  // Prologue: 4 halo rows + fill the FIFO, all loads issued back-to-back.
  float2 La, Ma, Ra, Lb, Mb, Rb, Lc, Mc, Rc, Ld, Md, Rd;
  loadrow(r0 - 2, La, Ma, Ra);
  loadrow(r0 - 1, Lb, Mb, Rb);
  loadrow(r0    , Lc, Mc, Rc);
  loadrow(r0 + 1, Ld, Md, Rd);
#pragma unroll
  for (int i = 0; i < PD; ++i) loadrow(r0 + 2 + i, Lf[i], Mf[i], Rf[i]);
  hfilt(La, Ma, Ra, A[0], B[0], C[0], D[0]);
  hfilt(Lb, Mb, Rb, A[1], B[1], C[1], D[1]);
  hfilt(Lc, Mc, Rc, A[2], B[2], C[2], D[2]);
  hfilt(Ld, Md, Rd, A[3], B[3], C[3], D[3]);

#pragma unroll
  for (int p = 0; p < RP; ++p) {
    hfilt(Lf[0], Mf[0], Rf[0], A[4], B[4], C[4], D[4]);  // consume FIFO head

    // Shift FIFO and issue the refill load (PD rows ahead).
#pragma unroll
    for (int k = 0; k + 1 < PD; ++k) {
      Lf[k] = Lf[k + 1]; Mf[k] = Mf[k + 1]; Rf[k] = Rf[k + 1];
    }
    if (p + PD < RP)
      loadrow(r0 + 2 + PD + p, Lf[PD - 1], Mf[PD - 1], Rf[PD - 1]);

    f32x4 ev, od;
    ev.x = A[0]*E0 + A[1]*E1 + A[2]*E2 + A[3]*E3 + A[4]*E4;
    ev.y = B[0]*E0 + B[1]*E1 + B[2]*E2 + B[3]*E3 + B[4]*E4;
    ev.z = C[0]*E0 + C[1]*E1 + C[2]*E2 + C[3]*E3 + C[4]*E4;
    ev.w = D[0]*E0 + D[1]*E1 + D[2]*E2 + D[3]*E3 + D[4]*E4;
    od.x = A[1]*O0 + A[2]*O1 + A[3]*O2 + A[4]*O3;
    od.y = B[1]*O0 + B[2]*O1 + B[3]*O2 + B[4]*O3;
    od.z = C[1]*O0 + C[2]*O1 + C[3]*O2 + C[4]*O3;
    od.w = D[1]*O0 + D[2]*O1 + D[3]*O2 + D[4]*O3;

    const int row_e = 2 * (r0 + p);
    f32x4* pe = reinterpret_cast<f32x4*>(&outb[(size_t)row_e       * (2 * W) + 4 * tid]);
    f32x4* po = reinterpret_cast<f32x4*>(&outb[(size_t)(row_e + 1) * (2 * W) + 4 * tid]);
    __builtin_nontemporal_store(ev, pe);
    __builtin_nontemporal_store(od, po);

#pragma unroll
    for (int k = 0; k < 4; ++k) {
      A[k] = A[k + 1]; B[k] = B[k + 1]; C[k] = C[k + 1]; D[k] = D[k + 1];
    }
  }
}

extern "C" void kernel_launch(void* const* d_in, const int* in_sizes, int n_in,
                              void* d_out, int out_size, void* d_ws, size_t ws_size,
                              hipStream_t stream) {
  const float* in = (const float*)d_in[0];
  float* out = (float*)d_out;
  const int batch = in_sizes[0] / (H * W);
  dim3 grid(H / RP, batch);   // 64 x 16 = 1024 blocks -> 4 blocks/CU
  bior_up_kernel<<<grid, 256, 0, stream>>>(in, out);
}